// Round 3
// baseline (422.746 us; speedup 1.0000x reference)
//
#include <hip/hip_runtime.h>
#include <hip/hip_bf16.h>

typedef __attribute__((ext_vector_type(8))) short short8;
typedef __attribute__((ext_vector_type(4))) float floatx4;
typedef __attribute__((ext_vector_type(4))) unsigned short ushortx4;

// workspace layout (bytes)
#define WS_W2 0        // bf16 [64][192]   : W2[co][k*64+c] = Wc[k*64+co][c]
#define WS_AE 24576    // bf16 [3][32][32] : ae[k][w][v] = Aeff[k][v][w], zero-padded
#define WS_F  30720    // f32  [32][64]    : F[w][co] = s*bterm + beta - mean*s (rows>=25 = 0)
#define WS_S  38912    // f32  [64]        : s[co] = gamma*rsqrt(var+eps)

__device__ __forceinline__ float bf2f(unsigned short u) {
    return __uint_as_float(((unsigned int)u) << 16);
}
__device__ __forceinline__ unsigned short f2bf(float f) {
    unsigned int xx = __float_as_uint(f);
    return (unsigned short)((xx + 0x7fffu + ((xx >> 16) & 1u)) >> 16);
}

// ---------------- prep: fold all constants once ----------------
__global__ __launch_bounds__(256) void gcn_prep(
    const float* __restrict__ A, const float* __restrict__ PA,
    const float* __restrict__ Wc, const float* __restrict__ bc,
    const float* __restrict__ gamma_, const float* __restrict__ beta_,
    const float* __restrict__ mean_, const float* __restrict__ var_,
    unsigned short* __restrict__ w2, unsigned short* __restrict__ ae,
    float* __restrict__ Fx, float* __restrict__ sarr)
{
    const int b = blockIdx.x, tid = threadIdx.x;
    if (b == 0) {
        __shared__ float cs[96];
        if (tid < 96) {
            int k = tid >> 5, w = tid & 31;
            float s = 0.f;
            if (w < 25)
                for (int v = 0; v < 25; ++v) {
                    int ai = (k * 25 + v) * 25 + w;
                    s += A[ai] * PA[ai];
                }
            cs[tid] = s;
        }
        if (tid < 64) sarr[tid] = gamma_[tid] * rsqrtf(var_[tid] + 1e-5f);
        __syncthreads();
        for (int e = tid; e < 2048; e += 256) {
            int w = e >> 6, co = e & 63;
            float val = 0.f;
            if (w < 25) {
                float sc = gamma_[co] * rsqrtf(var_[co] + 1e-5f);
                val = beta_[co] - mean_[co] * sc
                    + sc * (bc[co] * cs[w] + bc[64 + co] * cs[32 + w] + bc[128 + co] * cs[64 + w]);
            }
            Fx[e] = val;
        }
    } else if (b == 1) {
        for (int e = tid; e < 3072; e += 256) {
            int k = e >> 10, r = e & 1023, w = r >> 5, v = r & 31;
            unsigned short val = 0;
            if (v < 25 && w < 25) {
                int ai = (k * 25 + v) * 25 + w;
                val = f2bf(A[ai] * PA[ai]);
            }
            ae[e] = val;  // [k][w][v] holds Aeff[k][v][w]
        }
    } else {
        const int half = b - 2;
        for (int e = tid + half * 6144; e < (half + 1) * 6144; e += 256) {
            int co = e / 192, kc = e % 192, k = kc >> 6, c = kc & 63;
            w2[e] = f2bf(Wc[(k * 64 + co) * 64 + c]);
        }
    }
}

// ---------------- main: TT=8, 2 t per wave, wt-split passes ----------------
// LDS: Xs 32768 (swizzled, no pad) + XAbuf 8 chains x 1KB = 40960 B -> 4 blocks/CU
// Xs layout: half index = c*256 + ((t*4 + vchunk) ^ (c&7))*8 + (v&7)   [16B-chunk XOR swizzle]
__global__ __launch_bounds__(256, 4) void gcn_main(
    const float* __restrict__ x,
    const unsigned short* __restrict__ w2g,
    const unsigned short* __restrict__ aeg,
    const float* __restrict__ Fg,
    const float* __restrict__ sg,
    float* __restrict__ out)
{
#if defined(__gfx950__)
    __shared__ __align__(16) unsigned short Xs[64 * 256];
    __shared__ __align__(16) unsigned short XAbuf[8 * 512];   // halves; 1KB per chain

    const int tid = threadIdx.x;
    const int n  = blockIdx.x >> 5;
    const int t0 = (blockIdx.x & 31) * 8;
    const float* xn = x + (size_t)n * 409600;

    // ---- cooperative staging: 512 (c,t) rows, 2 per thread, swizzled b128 writes ----
#pragma unroll
    for (int i = 0; i < 2; ++i) {
        const int idx = tid + i * 256;
        const int c = idx >> 3, t = idx & 7;
        const float* gp = xn + (c * 256 + t0 + t) * 25;
        float f[32];
#pragma unroll
        for (int j = 0; j < 25; ++j) f[j] = gp[j];
#pragma unroll
        for (int j = 25; j < 32; ++j) f[j] = 0.f;
        unsigned short* base = &Xs[c * 256];
        const int sw = c & 7;
#pragma unroll
        for (int vc = 0; vc < 4; ++vc) {
            union { short8 v; unsigned short s[8]; } u;
#pragma unroll
            for (int j = 0; j < 8; ++j) u.s[j] = f2bf(f[vc * 8 + j]);
            *(short8*)&base[(((t * 4 + vc) ^ sw)) * 8] = u.v;
        }
    }
    __syncthreads();   // only barrier

    const int wave = tid >> 6, lane = tid & 63;
    const int l15 = lane & 15, quad = lane >> 4;
    const int tA = wave * 2, tB = wave * 2 + 1;
    const int swf = l15 & 7;                 // frag-read swizzle key (c&7 == l15&7)

    unsigned short* bufA = &XAbuf[(wave * 2 + 0) * 512];
    unsigned short* bufB = &XAbuf[(wave * 2 + 1) * 512];
    const int wlo3 = l15 & 3, qh = quad >> 1, ql = quad & 1;
    // half-offsets within a 16-row x 64B chain buffer
    const int woff0 = l15 * 32 + ((qh ^ wlo3) << 3) + (ql << 2);         // c-rows 0..15  (b64)
    const int woff1 = l15 * 32 + (((2 + qh) ^ wlo3) << 3) + (ql << 2);   // c-rows 16..31 (b64)
    const int roff  = l15 * 32 + ((quad ^ wlo3) << 3);                   // b128 read

    const floatx4 zero4 = {0.f, 0.f, 0.f, 0.f};

#pragma unroll 1
    for (int wt = 0; wt < 2; ++wt) {
        // Aeff B-fragments for this w-half: lane holds Aeff[k][v=quad*8+j][w=wt*16+l15]
        short8 aeff[3];
#pragma unroll
        for (int k = 0; k < 3; ++k)
            aeff[k] = *(const short8*)&aeg[(k * 32 + wt * 16 + l15) * 32 + quad * 8];

        floatx4 zA[4], zB[4];
#pragma unroll
        for (int ct = 0; ct < 4; ++ct) { zA[ct] = zero4; zB[ct] = zero4; }

#pragma unroll
        for (int ch = 0; ch < 6; ++ch) {
            const int k = ch >> 1, cc = ch & 1;
            const int c0 = cc * 32 + l15, c1 = cc * 32 + 16 + l15;

            // ---- stage A for both t-chains: XA[c',w] = X[c',v] @ Aeff_k[v,w] ----
            short8 x0A = *(const short8*)&Xs[c0 * 256 + ((tA * 4 + quad) ^ swf) * 8];
            short8 x1A = *(const short8*)&Xs[c1 * 256 + ((tA * 4 + quad) ^ swf) * 8];
            short8 x0B = *(const short8*)&Xs[c0 * 256 + ((tB * 4 + quad) ^ swf) * 8];
            short8 x1B = *(const short8*)&Xs[c1 * 256 + ((tB * 4 + quad) ^ swf) * 8];
            floatx4 dA0 = __builtin_amdgcn_mfma_f32_16x16x32_bf16(x0A, aeff[k], zero4, 0, 0, 0);
            floatx4 dA1 = __builtin_amdgcn_mfma_f32_16x16x32_bf16(x1A, aeff[k], zero4, 0, 0, 0);
            floatx4 dB0 = __builtin_amdgcn_mfma_f32_16x16x32_bf16(x0B, aeff[k], zero4, 0, 0, 0);
            floatx4 dB1 = __builtin_amdgcn_mfma_f32_16x16x32_bf16(x1B, aeff[k], zero4, 0, 0, 0);

            // ---- transpose through wave-private LDS (b64 packed writes) ----
            {
                ushortx4 p;
                p[0] = f2bf(dA0[0]); p[1] = f2bf(dA0[1]); p[2] = f2bf(dA0[2]); p[3] = f2bf(dA0[3]);
                *(ushortx4*)&bufA[woff0] = p;
                p[0] = f2bf(dA1[0]); p[1] = f2bf(dA1[1]); p[2] = f2bf(dA1[2]); p[3] = f2bf(dA1[3]);
                *(ushortx4*)&bufA[woff1] = p;
                p[0] = f2bf(dB0[0]); p[1] = f2bf(dB0[1]); p[2] = f2bf(dB0[2]); p[3] = f2bf(dB0[3]);
                *(ushortx4*)&bufB[woff0] = p;
                p[0] = f2bf(dB1[0]); p[1] = f2bf(dB1[1]); p[2] = f2bf(dB1[2]); p[3] = f2bf(dB1[3]);
                *(ushortx4*)&bufB[woff1] = p;
            }

            short8 bA = *(const short8*)&bufA[roff];
            short8 bB = *(const short8*)&bufB[roff];

            // ---- stage B: Z[co,w] += W2[co,kc] @ XA[kc,w], both chains share wf ----
            const unsigned short* wrow = &w2g[l15 * 192 + k * 64 + cc * 32 + quad * 8];
#pragma unroll
            for (int ct = 0; ct < 4; ++ct) {
                short8 wf = *(const short8*)&wrow[ct * 16 * 192];
                zA[ct] = __builtin_amdgcn_mfma_f32_16x16x32_bf16(wf, bA, zA[ct], 0, 0, 0);
                zB[ct] = __builtin_amdgcn_mfma_f32_16x16x32_bf16(wf, bB, zB[ct], 0, 0, 0);
            }
        }

        // ---- epilogue for this w-half, both t-chains ----
        const int w = wt * 16 + l15;
        if (wt == 0 || l15 < 9) {
#pragma unroll
            for (int tc = 0; tc < 2; ++tc) {
                const int t = (tc == 0) ? tA : tB;
                const floatx4* z = (tc == 0) ? zA : zB;
#pragma unroll
                for (int ct = 0; ct < 4; ++ct) {
                    floatx4 sv = *(const floatx4*)&sg[ct * 16 + quad * 4];
                    floatx4 Fv = *(const floatx4*)&Fg[w * 64 + ct * 16 + quad * 4];
#pragma unroll
                    for (int r = 0; r < 4; ++r) {
                        const int co = ct * 16 + quad * 4 + r;
                        float xres = bf2f(Xs[co * 256 + (((t * 4 + (w >> 3)) ^ (co & 7)) * 8) + (w & 7)]);
                        float val = sv[r] * z[ct][r] + Fv[r] + xres;
                        out[((size_t)(n * 64 + co) * 256 + t0 + t) * 25 + w] = fmaxf(val, 0.f);
                    }
                }
            }
        }
    }
#else
    (void)x; (void)w2g; (void)aeg; (void)Fg; (void)sg; (void)out;
#endif
}

extern "C" void kernel_launch(void* const* d_in, const int* in_sizes, int n_in,
                              void* d_out, int out_size, void* d_ws, size_t ws_size,
                              hipStream_t stream) {
    (void)in_sizes; (void)n_in; (void)out_size; (void)ws_size;
    unsigned short* w2 = (unsigned short*)((char*)d_ws + WS_W2);
    unsigned short* ae = (unsigned short*)((char*)d_ws + WS_AE);
    float*          Fx = (float*)((char*)d_ws + WS_F);
    float*          sa = (float*)((char*)d_ws + WS_S);

    gcn_prep<<<dim3(4), dim3(256), 0, stream>>>(
        (const float*)d_in[1], (const float*)d_in[2], (const float*)d_in[3],
        (const float*)d_in[4], (const float*)d_in[5], (const float*)d_in[6],
        (const float*)d_in[7], (const float*)d_in[8], w2, ae, Fx, sa);

    gcn_main<<<dim3(64 * 32), dim3(256), 0, stream>>>(
        (const float*)d_in[0], w2, ae, Fx, sa, (float*)d_out);
}

// Round 4
// 421.781 us; speedup vs baseline: 1.0023x; 1.0023x over previous
//
#include <hip/hip_runtime.h>
#include <hip/hip_bf16.h>

typedef __attribute__((ext_vector_type(8))) short short8;
typedef __attribute__((ext_vector_type(4))) float floatx4;
typedef __attribute__((ext_vector_type(4))) unsigned short ushortx4;

// workspace layout (bytes)
#define WS_W2 0        // bf16 [64][192]   : W2[co][k*64+c] = Wc[k*64+co][c]
#define WS_AE 24576    // bf16 [3][32][32] : ae[k][w][v] = Aeff[k][v][w], zero-padded
#define WS_F  30720    // f32  [32][64]    : F[w][co] = s*bterm + beta - mean*s (rows>=25 = 0)
#define WS_S  38912    // f32  [64]        : s[co] = gamma*rsqrt(var+eps)

__device__ __forceinline__ float bf2f(unsigned short u) {
    return __uint_as_float(((unsigned int)u) << 16);
}
__device__ __forceinline__ unsigned short f2bf(float f) {
    unsigned int xx = __float_as_uint(f);
    return (unsigned short)((xx + 0x7fffu + ((xx >> 16) & 1u)) >> 16);
}

// ---------------- prep: fold all constants once ----------------
__global__ __launch_bounds__(256) void gcn_prep(
    const float* __restrict__ A, const float* __restrict__ PA,
    const float* __restrict__ Wc, const float* __restrict__ bc,
    const float* __restrict__ gamma_, const float* __restrict__ beta_,
    const float* __restrict__ mean_, const float* __restrict__ var_,
    unsigned short* __restrict__ w2, unsigned short* __restrict__ ae,
    float* __restrict__ Fx, float* __restrict__ sarr)
{
    const int b = blockIdx.x, tid = threadIdx.x;
    if (b == 0) {
        __shared__ float cs[96];
        if (tid < 96) {
            int k = tid >> 5, w = tid & 31;
            float s = 0.f;
            if (w < 25)
                for (int v = 0; v < 25; ++v) {
                    int ai = (k * 25 + v) * 25 + w;
                    s += A[ai] * PA[ai];
                }
            cs[tid] = s;
        }
        if (tid < 64) sarr[tid] = gamma_[tid] * rsqrtf(var_[tid] + 1e-5f);
        __syncthreads();
        for (int e = tid; e < 2048; e += 256) {
            int w = e >> 6, co = e & 63;
            float val = 0.f;
            if (w < 25) {
                float sc = gamma_[co] * rsqrtf(var_[co] + 1e-5f);
                val = beta_[co] - mean_[co] * sc
                    + sc * (bc[co] * cs[w] + bc[64 + co] * cs[32 + w] + bc[128 + co] * cs[64 + w]);
            }
            Fx[e] = val;
        }
    } else if (b == 1) {
        for (int e = tid; e < 3072; e += 256) {
            int k = e >> 10, r = e & 1023, w = r >> 5, v = r & 31;
            unsigned short val = 0;
            if (v < 25 && w < 25) {
                int ai = (k * 25 + v) * 25 + w;
                val = f2bf(A[ai] * PA[ai]);
            }
            ae[e] = val;  // [k][w][v] holds Aeff[k][v][w]
        }
    } else {
        const int half = b - 2;
        for (int e = tid + half * 6144; e < (half + 1) * 6144; e += 256) {
            int co = e / 192, kc = e % 192, k = kc >> 6, c = kc & 63;
            w2[e] = f2bf(Wc[(k * 64 + co) * 64 + c]);
        }
    }
}

// ---------------- main: TT=8, 2 t per wave, wt-split passes ----------------
// LDS: Xs 32768 (swizzled, no pad) + XAbuf 8 chains x 1KB = 40960 B -> 4 blocks/CU
// Xs layout: half index = c*256 + ((t*4 + vchunk) ^ (c&7))*8 + (v&7)   [16B-chunk XOR swizzle]
__global__ __launch_bounds__(256, 4) void gcn_main(
    const float* __restrict__ x,
    const unsigned short* __restrict__ w2g,
    const unsigned short* __restrict__ aeg,
    const float* __restrict__ Fg,
    const float* __restrict__ sg,
    float* __restrict__ out)
{
#if defined(__gfx950__)
    __shared__ __align__(16) unsigned short Xs[64 * 256];
    __shared__ __align__(16) unsigned short XAbuf[8 * 512];   // halves; 1KB per chain

    const int tid = threadIdx.x;
    const int n  = blockIdx.x >> 5;
    const int t0 = (blockIdx.x & 31) * 8;
    const float* xn = x + (size_t)n * 409600;

    // ---- cooperative staging: 512 (c,t) rows, 2 per thread, swizzled b128 writes ----
#pragma unroll
    for (int i = 0; i < 2; ++i) {
        const int idx = tid + i * 256;
        const int c = idx >> 3, t = idx & 7;
        const float* gp = xn + (c * 256 + t0 + t) * 25;
        float f[32];
#pragma unroll
        for (int j = 0; j < 25; ++j) f[j] = gp[j];
#pragma unroll
        for (int j = 25; j < 32; ++j) f[j] = 0.f;
        unsigned short* base = &Xs[c * 256];
        const int sw = c & 7;
#pragma unroll
        for (int vc = 0; vc < 4; ++vc) {
            union { short8 v; unsigned short s[8]; } u;
#pragma unroll
            for (int j = 0; j < 8; ++j) u.s[j] = f2bf(f[vc * 8 + j]);
            *(short8*)&base[(((t * 4 + vc) ^ sw)) * 8] = u.v;
        }
    }
    __syncthreads();   // only barrier

    const int wave = tid >> 6, lane = tid & 63;
    const int l15 = lane & 15, quad = lane >> 4;
    const int tA = wave * 2, tB = wave * 2 + 1;
    const int swf = l15 & 7;                 // frag-read swizzle key (c&7 == l15&7)

    unsigned short* bufA = &XAbuf[(wave * 2 + 0) * 512];
    unsigned short* bufB = &XAbuf[(wave * 2 + 1) * 512];
    const int wlo3 = l15 & 3, qh = quad >> 1, ql = quad & 1;
    // half-offsets within a 16-row x 64B chain buffer
    const int woff0 = l15 * 32 + ((qh ^ wlo3) << 3) + (ql << 2);         // c-rows 0..15  (b64)
    const int woff1 = l15 * 32 + (((2 + qh) ^ wlo3) << 3) + (ql << 2);   // c-rows 16..31 (b64)
    const int roff  = l15 * 32 + ((quad ^ wlo3) << 3);                   // b128 read

    const floatx4 zero4 = {0.f, 0.f, 0.f, 0.f};

// epilogue with STATICALLY-NAMED accumulator array (rule #20: no runtime
// pointer/index into register arrays — zz must be an identifier, indices
// unroll-time constants)
#define EPILOGUE(zz, tcur)                                                          \
    do {                                                                            \
        _Pragma("unroll")                                                           \
        for (int ct = 0; ct < 4; ++ct) {                                            \
            floatx4 sv = *(const floatx4*)&sg[ct * 16 + quad * 4];                  \
            floatx4 Fv = *(const floatx4*)&Fg[w * 64 + ct * 16 + quad * 4];         \
            _Pragma("unroll")                                                       \
            for (int r = 0; r < 4; ++r) {                                           \
                const int co = ct * 16 + quad * 4 + r;                              \
                float xres = bf2f(Xs[co * 256 +                                     \
                    ((((tcur) * 4 + (w >> 3)) ^ (co & 7)) * 8) + (w & 7)]);         \
                float val = sv[r] * zz[ct][r] + Fv[r] + xres;                       \
                out[((size_t)(n * 64 + co) * 256 + t0 + (tcur)) * 25 + w] =         \
                    fmaxf(val, 0.f);                                                \
            }                                                                       \
        }                                                                           \
    } while (0)

#pragma unroll 1
    for (int wt = 0; wt < 2; ++wt) {
        // Aeff B-fragments for this w-half: lane holds Aeff[k][v=quad*8+j][w=wt*16+l15]
        short8 aeff[3];
#pragma unroll
        for (int k = 0; k < 3; ++k)
            aeff[k] = *(const short8*)&aeg[(k * 32 + wt * 16 + l15) * 32 + quad * 8];

        floatx4 zA[4], zB[4];
#pragma unroll
        for (int ct = 0; ct < 4; ++ct) { zA[ct] = zero4; zB[ct] = zero4; }

#pragma unroll
        for (int ch = 0; ch < 6; ++ch) {
            const int k = ch >> 1, cc = ch & 1;
            const int c0 = cc * 32 + l15, c1 = cc * 32 + 16 + l15;

            // ---- stage A for both t-chains: XA[c',w] = X[c',v] @ Aeff_k[v,w] ----
            short8 x0A = *(const short8*)&Xs[c0 * 256 + ((tA * 4 + quad) ^ swf) * 8];
            short8 x1A = *(const short8*)&Xs[c1 * 256 + ((tA * 4 + quad) ^ swf) * 8];
            short8 x0B = *(const short8*)&Xs[c0 * 256 + ((tB * 4 + quad) ^ swf) * 8];
            short8 x1B = *(const short8*)&Xs[c1 * 256 + ((tB * 4 + quad) ^ swf) * 8];
            floatx4 dA0 = __builtin_amdgcn_mfma_f32_16x16x32_bf16(x0A, aeff[k], zero4, 0, 0, 0);
            floatx4 dA1 = __builtin_amdgcn_mfma_f32_16x16x32_bf16(x1A, aeff[k], zero4, 0, 0, 0);
            floatx4 dB0 = __builtin_amdgcn_mfma_f32_16x16x32_bf16(x0B, aeff[k], zero4, 0, 0, 0);
            floatx4 dB1 = __builtin_amdgcn_mfma_f32_16x16x32_bf16(x1B, aeff[k], zero4, 0, 0, 0);

            // ---- transpose through wave-private LDS (b64 packed writes) ----
            {
                ushortx4 p;
                p[0] = f2bf(dA0[0]); p[1] = f2bf(dA0[1]); p[2] = f2bf(dA0[2]); p[3] = f2bf(dA0[3]);
                *(ushortx4*)&bufA[woff0] = p;
                p[0] = f2bf(dA1[0]); p[1] = f2bf(dA1[1]); p[2] = f2bf(dA1[2]); p[3] = f2bf(dA1[3]);
                *(ushortx4*)&bufA[woff1] = p;
                p[0] = f2bf(dB0[0]); p[1] = f2bf(dB0[1]); p[2] = f2bf(dB0[2]); p[3] = f2bf(dB0[3]);
                *(ushortx4*)&bufB[woff0] = p;
                p[0] = f2bf(dB1[0]); p[1] = f2bf(dB1[1]); p[2] = f2bf(dB1[2]); p[3] = f2bf(dB1[3]);
                *(ushortx4*)&bufB[woff1] = p;
            }

            short8 bA = *(const short8*)&bufA[roff];
            short8 bB = *(const short8*)&bufB[roff];

            // ---- stage B: Z[co,w] += W2[co,kc] @ XA[kc,w], both chains share wf ----
            const unsigned short* wrow = &w2g[l15 * 192 + k * 64 + cc * 32 + quad * 8];
#pragma unroll
            for (int ct = 0; ct < 4; ++ct) {
                short8 wf = *(const short8*)&wrow[ct * 16 * 192];
                zA[ct] = __builtin_amdgcn_mfma_f32_16x16x32_bf16(wf, bA, zA[ct], 0, 0, 0);
                zB[ct] = __builtin_amdgcn_mfma_f32_16x16x32_bf16(wf, bB, zB[ct], 0, 0, 0);
            }
        }

        // ---- epilogue for this w-half, both t-chains (statically-named accs) ----
        const int w = wt * 16 + l15;
        if (wt == 0 || l15 < 9) {
            EPILOGUE(zA, tA);
            EPILOGUE(zB, tB);
        }
    }
#undef EPILOGUE
#else
    (void)x; (void)w2g; (void)aeg; (void)Fg; (void)sg; (void)out;
#endif
}

extern "C" void kernel_launch(void* const* d_in, const int* in_sizes, int n_in,
                              void* d_out, int out_size, void* d_ws, size_t ws_size,
                              hipStream_t stream) {
    (void)in_sizes; (void)n_in; (void)out_size; (void)ws_size;
    unsigned short* w2 = (unsigned short*)((char*)d_ws + WS_W2);
    unsigned short* ae = (unsigned short*)((char*)d_ws + WS_AE);
    float*          Fx = (float*)((char*)d_ws + WS_F);
    float*          sa = (float*)((char*)d_ws + WS_S);

    gcn_prep<<<dim3(4), dim3(256), 0, stream>>>(
        (const float*)d_in[1], (const float*)d_in[2], (const float*)d_in[3],
        (const float*)d_in[4], (const float*)d_in[5], (const float*)d_in[6],
        (const float*)d_in[7], (const float*)d_in[8], w2, ae, Fx, sa);

    gcn_main<<<dim3(64 * 32), dim3(256), 0, stream>>>(
        (const float*)d_in[0], w2, ae, Fx, sa, (float*)d_out);
}

// Round 8
// 251.994 us; speedup vs baseline: 1.6776x; 1.6738x over previous
//
#include <hip/hip_runtime.h>
#include <hip/hip_bf16.h>

typedef __attribute__((ext_vector_type(8))) short short8;
typedef __attribute__((ext_vector_type(4))) float floatx4;
typedef __attribute__((ext_vector_type(4))) unsigned short ushortx4;

// workspace layout (bytes)
#define WS_W2 0        // bf16 [64][192]   : W2[co][k*64+c] = Wc[k*64+co][c]
#define WS_AE 24576    // bf16 [3][32][32] : ae[k][w][v] = Aeff[k][v][w], zero-padded
#define WS_F  30720    // f32  [32][64]    : F[w][co] = s*bterm + beta - mean*s
#define WS_S  38912    // f32  [64]        : s[co] = gamma*rsqrt(var+eps)

__device__ __forceinline__ float bf2f(unsigned short u) {
    return __uint_as_float(((unsigned int)u) << 16);
}
__device__ __forceinline__ unsigned short f2bf(float f) {
    unsigned int xx = __float_as_uint(f);
    return (unsigned short)((xx + 0x7fffu + ((xx >> 16) & 1u)) >> 16);
}

// ---------------- prep: fold all constants once (verified) ----------------
__global__ __launch_bounds__(256) void gcn_prep(
    const float* __restrict__ A, const float* __restrict__ PA,
    const float* __restrict__ Wc, const float* __restrict__ bc,
    const float* __restrict__ gamma_, const float* __restrict__ beta_,
    const float* __restrict__ mean_, const float* __restrict__ var_,
    unsigned short* __restrict__ w2, unsigned short* __restrict__ ae,
    float* __restrict__ Fx, float* __restrict__ sarr)
{
    const int b = blockIdx.x, tid = threadIdx.x;
    if (b == 0) {
        __shared__ float cs[96];
        if (tid < 96) {
            int k = tid >> 5, w = tid & 31;
            float s = 0.f;
            if (w < 25)
                for (int v = 0; v < 25; ++v) {
                    int ai = (k * 25 + v) * 25 + w;
                    s += A[ai] * PA[ai];
                }
            cs[tid] = s;
        }
        if (tid < 64) sarr[tid] = gamma_[tid] * rsqrtf(var_[tid] + 1e-5f);
        __syncthreads();
        for (int e = tid; e < 2048; e += 256) {
            int w = e >> 6, co = e & 63;
            float val = 0.f;
            if (w < 25) {
                float sc = gamma_[co] * rsqrtf(var_[co] + 1e-5f);
                val = beta_[co] - mean_[co] * sc
                    + sc * (bc[co] * cs[w] + bc[64 + co] * cs[32 + w] + bc[128 + co] * cs[64 + w]);
            }
            Fx[e] = val;
        }
    } else if (b == 1) {
        for (int e = tid; e < 3072; e += 256) {
            int k = e >> 10, r = e & 1023, w = r >> 5, v = r & 31;
            unsigned short val = 0;
            if (v < 25 && w < 25) {
                int ai = (k * 25 + v) * 25 + w;
                val = f2bf(A[ai] * PA[ai]);
            }
            ae[e] = val;  // [k][w][v] holds Aeff[k][v][w]
        }
    } else {
        const int half = b - 2;
        for (int e = tid + half * 6144; e < (half + 1) * 6144; e += 256) {
            int co = e / 192, kc = e % 192, k = kc >> 6, c = kc & 63;
            w2[e] = f2bf(Wc[(k * 64 + co) * 64 + c]);
        }
    }
}

// ---------------- main: R2 main loop + coalesced 3-phase staging + W2 in LDS ----------------
// LDS map (50176 B total -> 3 blocks/CU):
//   [0,16384)      Xs   bf16 [64][128], chunk swizzle key = c&7  (R4-verified form)
//   [16384,24576)  XA   4 waves x 2048 B (single buffer per wave)
//   [24576,50176)  W2s  bf16 [64] rows, pitch 200 shorts (100 dw % 32 = 4 -> even banks)
//   [16384,41984)  T    f32 x-tile, phases 1-2 only (aliases XA + W2s front; dead after)
__global__ __launch_bounds__(256, 3) void gcn_main(
    const float* __restrict__ x,
    const unsigned short* __restrict__ w2g,
    const unsigned short* __restrict__ aeg,
    const float* __restrict__ Fg,
    const float* __restrict__ sg,
    float* __restrict__ out)
{
#if defined(__gfx950__)
    __shared__ __align__(16) unsigned char LB[50176];
    unsigned short* Xs  = (unsigned short*)LB;
    unsigned short* XA  = (unsigned short*)(LB + 16384);
    unsigned short* W2s = (unsigned short*)(LB + 24576);
    float*          T   = (float*)(LB + 16384);

    const int tid = threadIdx.x;
    const int n  = blockIdx.x >> 6;
    const int t0 = (blockIdx.x & 63) * 4;
    const float* xn = x + (size_t)n * 409600;

    const int wave = tid >> 6, lane = tid & 63;
    const int l15 = lane & 15, quad = lane >> 4;

    // Aeff fragments from global (3 KB, L2-hot); issue early.
    short8 aeff[3][2];
#pragma unroll
    for (int k = 0; k < 3; ++k)
#pragma unroll
        for (int nt = 0; nt < 2; ++nt)
            aeff[k][nt] = *(const short8*)&aeg[(k * 32 + nt * 16 + l15) * 32 + quad * 8];

    // ---- phase 1: coalesced float4 x-tile -> T (f32) ----
    // tile = 64 segments (one per c) of 100 contiguous floats; seg base 16B-aligned (t0 % 4 == 0)
#pragma unroll
    for (int i = 0; i < 7; ++i) {
        int q = tid + (i << 8);          // float4 index, 1600 total
        if (q < 1600) {
            int c = q / 25, j = q % 25;
            *(floatx4*)&T[q * 4] = *(const floatx4*)&xn[c * 6400 + t0 * 25 + j * 4];
        }
    }
    __syncthreads();

    // ---- phase 2: T -> Xs bf16, swizzled b128 writes ----
    {
        const int c = tid >> 2, tl = tid & 3, key = c & 7;
        const float* tr = &T[c * 100 + tl * 25];
        float f[32];
#pragma unroll
        for (int j = 0; j < 25; ++j) f[j] = tr[j];
#pragma unroll
        for (int j = 25; j < 32; ++j) f[j] = 0.f;
#pragma unroll
        for (int vc = 0; vc < 4; ++vc) {
            union { short8 v; unsigned short s[8]; } u;
#pragma unroll
            for (int j = 0; j < 8; ++j) u.s[j] = f2bf(f[vc * 8 + j]);
            *(short8*)&Xs[c * 128 + (((tl * 4 + vc) ^ key) << 3)] = u.v;
        }
    }
    __syncthreads();   // T dead after this point

    // ---- phase 3: w2g -> W2s (pitch 200, linear chunks, coalesced 16B reads) ----
    {
        const int co = tid >> 2, g = tid & 3;
#pragma unroll
        for (int jj = 0; jj < 6; ++jj) {
            int j = g * 6 + jj;          // 24 chunks of 8 shorts per row
            *(short8*)&W2s[co * 200 + j * 8] = *(const short8*)&w2g[co * 192 + j * 8];
        }
    }
    __syncthreads();

    // ---- main loop: R2-verbatim structure, wave-private t ----
    const int t = wave;
    char* xab = (char*)XA + wave * 2048;
    const int wlo3 = l15 & 3, qh = quad >> 1, ql = quad & 1;
    const int woff00 = l15 * 64        + ((qh ^ wlo3) << 4) + ql * 8;        // c 0..15
    const int woff01 = (16 + l15) * 64 + ((qh ^ wlo3) << 4) + ql * 8;
    const int woff10 = l15 * 64        + (((2 + qh) ^ wlo3) << 4) + ql * 8;  // c 16..31
    const int woff11 = (16 + l15) * 64 + (((2 + qh) ^ wlo3) << 4) + ql * 8;
    const int roff0  = l15 * 64        + ((quad ^ wlo3) << 4);
    const int roff1  = (16 + l15) * 64 + ((quad ^ wlo3) << 4);
    const int xoffX  = ((t * 4 + quad) ^ (l15 & 7)) << 3;

    const floatx4 zero4 = {0.f, 0.f, 0.f, 0.f};
    floatx4 zacc[4][2];
#pragma unroll
    for (int ct = 0; ct < 4; ++ct) { zacc[ct][0] = zero4; zacc[ct][1] = zero4; }

#pragma unroll
    for (int ch = 0; ch < 6; ++ch) {
        const int k = ch >> 1, cc = ch & 1;
        const int c0 = cc * 32 + l15, c1 = c0 + 16;   // (c0&7)==(c1&7)==l15&7

        // stage A: XA[c,w] = X[c,v] @ Aeff_k[v,w]
        short8 xf0 = *(const short8*)&Xs[c0 * 128 + xoffX];
        short8 xf1 = *(const short8*)&Xs[c1 * 128 + xoffX];
        floatx4 d00 = __builtin_amdgcn_mfma_f32_16x16x32_bf16(xf0, aeff[k][0], zero4, 0, 0, 0);
        floatx4 d01 = __builtin_amdgcn_mfma_f32_16x16x32_bf16(xf0, aeff[k][1], zero4, 0, 0, 0);
        floatx4 d10 = __builtin_amdgcn_mfma_f32_16x16x32_bf16(xf1, aeff[k][0], zero4, 0, 0, 0);
        floatx4 d11 = __builtin_amdgcn_mfma_f32_16x16x32_bf16(xf1, aeff[k][1], zero4, 0, 0, 0);

        // transpose through wave-private LDS (b64 packed writes)
        {
            ushortx4 p;
            p[0] = f2bf(d00[0]); p[1] = f2bf(d00[1]); p[2] = f2bf(d00[2]); p[3] = f2bf(d00[3]);
            *(ushortx4*)(xab + woff00) = p;
            p[0] = f2bf(d01[0]); p[1] = f2bf(d01[1]); p[2] = f2bf(d01[2]); p[3] = f2bf(d01[3]);
            *(ushortx4*)(xab + woff01) = p;
            p[0] = f2bf(d10[0]); p[1] = f2bf(d10[1]); p[2] = f2bf(d10[2]); p[3] = f2bf(d10[3]);
            *(ushortx4*)(xab + woff10) = p;
            p[0] = f2bf(d11[0]); p[1] = f2bf(d11[1]); p[2] = f2bf(d11[2]); p[3] = f2bf(d11[3]);
            *(ushortx4*)(xab + woff11) = p;
        }
        short8 b0 = *(const short8*)(xab + roff0);
        short8 b1 = *(const short8*)(xab + roff1);

        // stage B: Z[co,w] += W2[co,kc] @ XA[kc,w]; wf from LDS
#pragma unroll
        for (int ct = 0; ct < 4; ++ct) {
            short8 wf = *(const short8*)&W2s[(ct * 16 + l15) * 200 + (k * 8 + cc * 4 + quad) * 8];
            zacc[ct][0] = __builtin_amdgcn_mfma_f32_16x16x32_bf16(wf, b0, zacc[ct][0], 0, 0, 0);
            zacc[ct][1] = __builtin_amdgcn_mfma_f32_16x16x32_bf16(wf, b1, zacc[ct][1], 0, 0, 0);
        }
    }

    // ---- epilogue: val = s[co]*z + F[w][co] + residual, relu ----
#pragma unroll
    for (int wt = 0; wt < 2; ++wt) {
        const int w = wt * 16 + l15;
        if (wt == 0 || l15 < 9) {
#pragma unroll
            for (int ct = 0; ct < 4; ++ct) {
                floatx4 sv = *(const floatx4*)&sg[ct * 16 + quad * 4];
                floatx4 Fv = *(const floatx4*)&Fg[w * 64 + ct * 16 + quad * 4];
#pragma unroll
                for (int r = 0; r < 4; ++r) {
                    const int co = ct * 16 + quad * 4 + r;
                    float xres = bf2f(Xs[co * 128 + (((t * 4 + (w >> 3)) ^ (co & 7)) << 3) + (w & 7)]);
                    float val = sv[r] * zacc[ct][wt][r] + Fv[r] + xres;
                    out[((size_t)(n * 64 + co) * 256 + t0 + t) * 25 + w] = fmaxf(val, 0.f);
                }
            }
        }
    }
#else
    (void)x; (void)w2g; (void)aeg; (void)Fg; (void)sg; (void)out;
#endif
}

extern "C" void kernel_launch(void* const* d_in, const int* in_sizes, int n_in,
                              void* d_out, int out_size, void* d_ws, size_t ws_size,
                              hipStream_t stream) {
    (void)in_sizes; (void)n_in; (void)out_size; (void)ws_size;
    unsigned short* w2 = (unsigned short*)((char*)d_ws + WS_W2);
    unsigned short* ae = (unsigned short*)((char*)d_ws + WS_AE);
    float*          Fx = (float*)((char*)d_ws + WS_F);
    float*          sa = (float*)((char*)d_ws + WS_S);

    gcn_prep<<<dim3(4), dim3(256), 0, stream>>>(
        (const float*)d_in[1], (const float*)d_in[2], (const float*)d_in[3],
        (const float*)d_in[4], (const float*)d_in[5], (const float*)d_in[6],
        (const float*)d_in[7], (const float*)d_in[8], w2, ae, Fx, sa);

    gcn_main<<<dim3(64 * 64), dim3(256), 0, stream>>>(
        (const float*)d_in[0], w2, ae, Fx, sa, (float*)d_out);
}